// Round 12
// baseline (403.537 us; speedup 1.0000x reference)
//
#include <hip/hip_runtime.h>
#include <hip/hip_bf16.h>
#include <math.h>

// ---------- helpers ----------
typedef __attribute__((ext_vector_type(8))) short short8;   // 8 bf16 = 4 VGPR (MFMA A/B frag)
typedef __attribute__((ext_vector_type(4))) float f32x4;    // MFMA C/D frag
typedef __attribute__((ext_vector_type(4))) int int4v;
typedef __attribute__((ext_vector_type(8))) int int8v;

__device__ __forceinline__ unsigned short f2b(float x) {    // fp32 -> bf16 bits, RNE
  union { float f; unsigned int u; } v; v.f = x;
  unsigned int r = v.u + 0x7fffu + ((v.u >> 16) & 1u);
  return (unsigned short)(r >> 16);
}
__device__ __forceinline__ float b2f(unsigned short u) {
  union { unsigned int u; float f; } v; v.u = ((unsigned int)u) << 16;
  return v.f;
}
// fp32 -> OCP e4m3fn byte (software fallback), RNE
__device__ __forceinline__ unsigned char f2f8_sw(float x) {
  float a = fabsf(x);
  unsigned char s = (x < 0.f) ? 0x80 : 0x00;
  if (a >= 464.f) return s | 0x7E;
  union { float f; unsigned u; } v; v.f = a;
  int e = (int)(v.u >> 23) - 127;
  if (e < -6) {
    int q = (int)rintf(a * 512.f);
    if (q >= 8) return s | 0x08;
    return s | (unsigned char)q;
  }
  unsigned mant = v.u & 0x7FFFFF;
  unsigned keep = mant >> 20;
  unsigned rest = mant & 0xFFFFF;
  if (rest > 0x80000u || (rest == 0x80000u && (keep & 1))) keep++;
  unsigned exp8 = (unsigned)(e + 7);
  if (keep == 8) { keep = 0; exp8++; }
  if (exp8 >= 15 && keep >= 7) return s | 0x7E;
  return s | (unsigned char)((exp8 << 3) | keep);
}
#if __has_builtin(__builtin_amdgcn_cvt_pk_fp8_f32)
__device__ __forceinline__ unsigned char f2f8(float x) {
  return (unsigned char)(__builtin_amdgcn_cvt_pk_fp8_f32(x, x, 0, false) & 0xFF);
}
__device__ __forceinline__ unsigned int f8pack4(float a, float b, float c, float d) {
  int w0 = __builtin_amdgcn_cvt_pk_fp8_f32(a, b, 0, false);
  return (unsigned int)__builtin_amdgcn_cvt_pk_fp8_f32(c, d, w0, true);
}
#else
__device__ __forceinline__ unsigned char f2f8(float x) { return f2f8_sw(x); }
__device__ __forceinline__ unsigned int f8pack4(float a, float b, float c, float d) {
  return (unsigned)f2f8_sw(a) | ((unsigned)f2f8_sw(b) << 8) |
         ((unsigned)f2f8_sw(c) << 16) | ((unsigned)f2f8_sw(d) << 24);
}
#endif
__device__ __forceinline__ void async_ld16(const void* g, void* l) {
  __builtin_amdgcn_global_load_lds(
      (const __attribute__((address_space(1))) void*)g,
      (__attribute__((address_space(3))) void*)l, 16, 0, 0);
}

// vectorized weight->fp8 rider: float4 load + packed uint store (G13).
__device__ __forceinline__ void conv_rider(
    const float* __restrict__ csrc, unsigned char* __restrict__ cdst,
    size_t ccount, size_t tidg, size_t nthr) {
  const float4* src4 = (const float4*)csrc;
  unsigned int* dst4 = (unsigned int*)cdst;
  const size_t ng = ccount >> 2;
  for (size_t id = tidg; id < ng; id += nthr) {
    const float4 v = src4[id];
    dst4[id] = f8pack4(v.x * 64.f, v.y * 64.f, v.z * 64.f, v.w * 64.f);
  }
}

// MX-scaled fp8 K=128 MFMA with unit scales (== exact fp8 GEMM at 2x rate).
__device__ __forceinline__ f32x4 mx8(int8v a, int8v b, f32x4 c) {
#if __has_builtin(__builtin_amdgcn_mfma_scale_f32_16x16x128_f8f6f4)
  return __builtin_amdgcn_mfma_scale_f32_16x16x128_f8f6f4(
      a, b, c, 0, 0, 0, 0x7F7F7F7F, 0, 0x7F7F7F7F);
#else
  union { int8v v; long l[4]; } av, bv; av.v = a; bv.v = b;
#pragma unroll
  for (int j = 0; j < 4; j++)
    c = __builtin_amdgcn_mfma_f32_16x16x32_fp8_fp8(av.l[j], bv.l[j], c, 0, 0, 0);
  return c;
#endif
}

// conflict-free fragment read: two b128 at 16B granules (2q)^(r&7), (2q+1)^(r&7).
__device__ __forceinline__ int8v rd8(const unsigned char* tb, int r, int q) {
  union { int8v v; int4v h[2]; } x;
  x.h[0] = *(const int4v*)(tb + (size_t)((r << 3) + ((2 * q)     ^ (r & 7))) * 16);
  x.h[1] = *(const int4v*)(tb + (size_t)((r << 3) + ((2 * q + 1) ^ (r & 7))) * 16);
  return x.v;
}

// ---------- prep (block 0) + Bb/Cb riders (1..32) + fused RMSNorm1 (33..) ----------
__global__ __launch_bounds__(1024) void prep_combo(
    const float* __restrict__ A, const float* __restrict__ logdt,
    float* __restrict__ Abar, float* __restrict__ A64,
    const float* __restrict__ B, const float* __restrict__ Cm,
    unsigned short* __restrict__ Bb, unsigned short* __restrict__ Cb,
    const float* __restrict__ x, const float* __restrict__ w1,
    unsigned short* __restrict__ xnb, float* __restrict__ rs_out) {
  __shared__ float red[16];
  __shared__ float Ms[4096], T[4096], P[4096];
  __shared__ float wsum2[16];
  const int tid = threadIdx.x;
  if (blockIdx.x >= 33) {                    // fused rmsnorm: 4 rows / block
    const int sub = tid >> 8, t = tid & 255;
    const size_t row = (size_t)(blockIdx.x - 33) * 4 + sub;
    const float4 v = ((const float4*)(x + row * 1024))[t];
    float ss = v.x * v.x + v.y * v.y + v.z * v.z + v.w * v.w;
#pragma unroll
    for (int off = 32; off > 0; off >>= 1) ss += __shfl_down(ss, off);
    if ((t & 63) == 0) wsum2[(sub << 2) | (t >> 6)] = ss;
    __syncthreads();
    const float tot = wsum2[sub << 2] + wsum2[(sub << 2) | 1] +
                      wsum2[(sub << 2) | 2] + wsum2[(sub << 2) | 3];
    const float rs = rsqrtf(tot * (1.f / 1024.f) + 1e-6f);
    if (t == 0) rs_out[row] = rs;
    const float4 wv = ((const float4*)w1)[t];
    ushort4 o;
    o.x = f2b(v.x * rs * wv.x); o.y = f2b(v.y * rs * wv.y);
    o.z = f2b(v.z * rs * wv.z); o.w = f2b(v.w * rs * wv.w);
    ((ushort4*)(xnb + row * 1024))[t] = o;
    return;
  }
  if (blockIdx.x != 0) {                     // Bb/Cb riders (32 blocks)
    const size_t NB = 65536, NC = 65536;
    size_t base = (size_t)(blockIdx.x - 1) * 1024 + tid;
    const size_t stride = 32 * 1024;
    for (size_t id = base; id < NB + NC; id += stride) {
      if (id < NB) { int k = (int)(id & 1023); Bb[id] = f2b(B[id] * expf(logdt[k])); }
      else Cb[id - NB] = f2b(Cm[id - NB]);
    }
    return;
  }
  const int c = tid & 63;
  const int w = tid >> 6;
  float e = expf(logdt[tid]);
#pragma unroll
  for (int off = 32; off > 0; off >>= 1) e += __shfl_down(e, off);
  if (c == 0) red[w] = e;
  __syncthreads();
  if (tid == 0) {
    float s = 0.f;
    for (int i = 0; i < 16; i++) s += red[i];
    red[0] = s * (1.f / 1024.f);
  }
  __syncthreads();
  const float mdt = red[0];
  {
    float m0 = A[tid] * mdt, m1 = A[tid + 1024] * mdt,
          m2 = A[tid + 2048] * mdt, m3 = A[tid + 3072] * mdt;
    Ms[tid] = m0; Ms[tid + 1024] = m1; Ms[tid + 2048] = m2; Ms[tid + 3072] = m3;
    T[tid] = m0; T[tid + 1024] = m1; T[tid + 2048] = m2; T[tid + 3072] = m3;
    P[tid] = m0 + ((tid >> 6) == (tid & 63) ? 1.f : 0.f);
    P[tid + 1024] = m1 + (((tid + 1024) >> 6) == ((tid + 1024) & 63) ? 1.f : 0.f);
    P[tid + 2048] = m2 + (((tid + 2048) >> 6) == ((tid + 2048) & 63) ? 1.f : 0.f);
    P[tid + 3072] = m3 + (((tid + 3072) >> 6) == ((tid + 3072) & 63) ? 1.f : 0.f);
  }
  __syncthreads();
  float colM[64];
#pragma unroll
  for (int j = 0; j < 64; j++) colM[j] = Ms[j * 64 + c];
  for (int k = 2; k <= 6; k++) {
    const float inv = 1.f / (float)k;
    float accs[4];
#pragma unroll
    for (int i = 0; i < 4; i++) {
      const int r = w + 16 * i;
      const float4* Trow = (const float4*)(T + r * 64);
      float a0 = 0.f, a1 = 0.f, a2 = 0.f, a3 = 0.f;
#pragma unroll
      for (int j4 = 0; j4 < 16; j4++) {
        const float4 t = Trow[j4];
        a0 += t.x * colM[4 * j4 + 0]; a1 += t.y * colM[4 * j4 + 1];
        a2 += t.z * colM[4 * j4 + 2]; a3 += t.w * colM[4 * j4 + 3];
      }
      accs[i] = ((a0 + a1) + (a2 + a3)) * inv;
    }
    __syncthreads();
#pragma unroll
    for (int i = 0; i < 4; i++) {
      const int r = w + 16 * i;
      T[r * 64 + c] = accs[i];
      P[r * 64 + c] += accs[i];
    }
    __syncthreads();
  }
#pragma unroll
  for (int i = 0; i < 4; i++) {
    const int r = w + 16 * i;
    Abar[r * 64 + c] = P[r * 64 + c];
    T[r * 64 + c] = P[r * 64 + c];
  }
  __syncthreads();
  for (int sq = 0; sq < 6; sq++) {
    float colT[64];
#pragma unroll
    for (int j = 0; j < 64; j++) colT[j] = T[j * 64 + c];
    float accs[4];
#pragma unroll
    for (int i = 0; i < 4; i++) {
      const int r = w + 16 * i;
      const float4* Trow = (const float4*)(T + r * 64);
      float a0 = 0.f, a1 = 0.f, a2 = 0.f, a3 = 0.f;
#pragma unroll
      for (int j4 = 0; j4 < 16; j4++) {
        const float4 t = Trow[j4];
        a0 += t.x * colT[4 * j4 + 0]; a1 += t.y * colT[4 * j4 + 1];
        a2 += t.z * colT[4 * j4 + 2]; a3 += t.w * colT[4 * j4 + 3];
      }
      accs[i] = (a0 + a1) + (a2 + a3);
    }
    __syncthreads();
#pragma unroll
    for (int i = 0; i < 4; i++) T[(w + 16 * i) * 64 + c] = accs[i];
    __syncthreads();
  }
#pragma unroll
  for (int i = 0; i < 4; i++) {
    const int r = w + 16 * i;
    A64[r * 64 + c] = T[r * 64 + c];
  }
}

// ---------- RMSNorm (row = 1024) -> fp8 e4m3 ----------
__global__ __launch_bounds__(256) void rmsnorm_f8(
    const float* __restrict__ x, const float* __restrict__ w,
    unsigned int* __restrict__ out) {       // 4 fp8 per uint
  const size_t row = blockIdx.x;
  const int tid = threadIdx.x;
  const float4 v = ((const float4*)(x + row * 1024))[tid];
  float ss = v.x * v.x + v.y * v.y + v.z * v.z + v.w * v.w;
#pragma unroll
  for (int off = 32; off > 0; off >>= 1) ss += __shfl_down(ss, off);
  __shared__ float wsum[4];
  if ((tid & 63) == 0) wsum[tid >> 6] = ss;
  __syncthreads();
  const float tot = wsum[0] + wsum[1] + wsum[2] + wsum[3];
  const float rs = rsqrtf(tot * (1.f / 1024.f) + 1e-6f);
  const float4 wv = ((const float4*)w)[tid];
  out[row * 256 + tid] =
      f8pack4(v.x * rs * wv.x, v.y * rs * wv.y, v.z * rs * wv.z, v.w * rs * wv.w);
}

// ---------- scan (32 blocks, 4 chunk-waves each) + fp8 weight-convert riders ----------
// Barrier-free (wave-private s-slice) + next-step prefetch; R6-verified.
template <int STORE_S>
__global__ __launch_bounds__(256) void scan_combo(
    const float* __restrict__ U, const float* __restrict__ Abar,
    const float* __restrict__ carry, float* __restrict__ zend,
    unsigned short* __restrict__ S,
    const float* __restrict__ csrc, unsigned char* __restrict__ cdst, size_t ccount) {
  constexpr int SCAN_BLOCKS = 32;
  __shared__ float s[4][64];
  if (blockIdx.x >= SCAN_BLOCKS) {
    conv_rider(csrc, cdst, ccount,
               (size_t)(blockIdx.x - SCAN_BLOCKS) * 256 + threadIdx.x,
               (size_t)(gridDim.x - SCAN_BLOCKS) * 256);
    return;
  }
  const int wave = threadIdx.x >> 6, i = threadIdx.x & 63;
  const int task = blockIdx.x * 4 + wave;
  const int b = task >> 5, c = task & 31;
  float a[64];
#pragma unroll
  for (int j = 0; j < 64; j++) a[j] = Abar[i * 64 + j];
  float cur = STORE_S ? carry[(b * 32 + c) * 64 + i] : 0.f;
  const float* Ub = U + ((size_t)(b * 2048 + c * 64)) * 64;
  float u = Ub[i];                          // prefetched element for t=0
  for (int t = 0; t < 64; t++) {
    s[wave][i] = cur;
    float u_next = 0.f;
    if (t + 1 < 64) u_next = Ub[(t + 1) * 64 + i];   // prefetch next step
    const float4* s4 = (const float4*)s[wave];
    float a0 = u, a1 = 0.f, a2 = 0.f, a3 = 0.f;
#pragma unroll
    for (int j = 0; j < 16; j++) {
      float4 v = s4[j];
      a0 += a[4 * j + 0] * v.x; a1 += a[4 * j + 1] * v.y;
      a2 += a[4 * j + 2] * v.z; a3 += a[4 * j + 3] * v.w;
    }
    cur = (a0 + a1) + (a2 + a3);
    if (STORE_S) S[((size_t)(b * 2048 + c * 64 + t)) * 64 + i] = f2b(cur);
    u = u_next;
  }
  if (!STORE_S) zend[(b * 32 + c) * 64 + i] = cur;
}

// ---------- carry recurrence (block 0) + fp8 weight-convert riders ----------
__global__ __launch_bounds__(256) void carry_combo(
    const float* __restrict__ zend, const float* __restrict__ A64,
    float* __restrict__ carry,
    const float* __restrict__ csrc, unsigned char* __restrict__ cdst, size_t ccount) {
  __shared__ float s[4][64];
  if (blockIdx.x != 0) {
    conv_rider(csrc, cdst, ccount,
               (size_t)(blockIdx.x - 1) * 256 + threadIdx.x,
               (size_t)(gridDim.x - 1) * 256);
    return;
  }
  const int b = threadIdx.x >> 6, i = threadIdx.x & 63;
  float a[64];
#pragma unroll
  for (int j = 0; j < 64; j++) a[j] = A64[i * 64 + j];
  float cur = 0.f;
  float z = zend[(b * 32 + 0) * 64 + i];
  for (int c = 0; c < 32; c++) {
    carry[(b * 32 + c) * 64 + i] = cur;
    s[b][i] = cur;
    float z_next = 0.f;
    if (c + 1 < 32) z_next = zend[(b * 32 + c + 1) * 64 + i];
    const float4* s4 = (const float4*)s[b];
    float a0 = z, a1 = 0.f, a2 = 0.f, a3 = 0.f;
#pragma unroll
    for (int j = 0; j < 16; j++) {
      float4 v = s4[j];
      a0 += a[4 * j + 0] * v.x; a1 += a[4 * j + 1] * v.y;
      a2 += a[4 * j + 2] * v.z; a3 += a[4 * j + 3] * v.w;
    }
    cur = (a0 + a1) + (a2 + a3);
    z = z_next;
  }
}

// ---------- bf16 MFMA GEMM:  C(M,N) = X(M,K) @ W(N,K)^T ----------
// EPI: 0 = fp32 store
//      5 = acc + e_f*(1 + e_d[n]*e_w[n]*e_r[m]) -> fp32
template <int BM, int BN, int WAVES_M, int WAVES_N, int EPI>
__global__ void __launch_bounds__(256) gemm_bt(
    const unsigned short* __restrict__ X, const unsigned short* __restrict__ W,
    int M, int N, int K,
    float* __restrict__ outf, const float* __restrict__ e_f,
    const float* __restrict__ e_d, const float* __restrict__ e_w,
    const float* __restrict__ e_r) {
  constexpr int BK = 64;
  constexpr int SM = BM / WAVES_M, SN = BN / WAVES_N;
  constexpr int TM = SM / 16, TN = SN / 16;
  __shared__ unsigned short aT[BM * BK];
  __shared__ unsigned short bT[BN * BK];
  const int tid = threadIdx.x;
  const int lane = tid & 63, wave = tid >> 6;
  const int wm = wave / WAVES_N, wn = wave % WAVES_N;
  const int lm = lane & 15, quad = lane >> 4;
  const long bm0 = (long)blockIdx.y * BM;
  const long bn0 = (long)blockIdx.x * BN;
  const int wb = tid & ~63;

  f32x4 acc[TM][TN];
#pragma unroll
  for (int i = 0; i < TM; i++)
#pragma unroll
    for (int j = 0; j < TN; j++) acc[i][j] = (f32x4){0.f, 0.f, 0.f, 0.f};

  for (int k0 = 0; k0 < K; k0 += BK) {
#pragma unroll
    for (int it = 0; it < (BM * 8) / 256; ++it) {
      int slot = it * 256 + tid;
      int r = slot >> 3, cp = slot & 7, c = cp ^ (r & 7);
      async_ld16(X + (bm0 + r) * (long)K + k0 + c * 8, aT + (it * 256 + wb) * 8);
    }
#pragma unroll
    for (int it = 0; it < (BN * 8) / 256; ++it) {
      int slot = it * 256 + tid;
      int r = slot >> 3, cp = slot & 7, c = cp ^ (r & 7);
      async_ld16(W + (bn0 + r) * (long)K + k0 + c * 8, bT + (it * 256 + wb) * 8);
    }
    __syncthreads();
#pragma unroll
    for (int kk = 0; kk < BK; kk += 32) {
      const int cch = (kk >> 3) + quad;
      short8 af[TM], bf[TN];
#pragma unroll
      for (int i = 0; i < TM; i++) {
        int r = wm * SM + i * 16 + lm;
        af[i] = *(const short8*)(aT + (r * 8 + (cch ^ (r & 7))) * 8);
      }
#pragma unroll
      for (int j = 0; j < TN; j++) {
        int r = wn * SN + j * 16 + lm;
        bf[j] = *(const short8*)(bT + (r * 8 + (cch ^ (r & 7))) * 8);
      }
#pragma unroll
      for (int i = 0; i < TM; i++)
#pragma unroll
        for (int j = 0; j < TN; j++)
          acc[i][j] = __builtin_amdgcn_mfma_f32_16x16x32_bf16(af[i], bf[j], acc[i][j], 0, 0, 0);
    }
    __syncthreads();
  }
#pragma unroll
  for (int i = 0; i < TM; i++) {
#pragma unroll
    for (int j = 0; j < TN; j++) {
#pragma unroll
      for (int r = 0; r < 4; r++) {
        const long m = bm0 + wm * SM + i * 16 + quad * 4 + r;
        const long n = bn0 + wn * SN + j * 16 + lm;
        const long idx = m * N + n;
        const float v = acc[i][j][r];
        if (EPI == 0) outf[idx] = v;
        else if (EPI == 5)
          outf[idx] = v + e_f[idx] * (1.f + e_d[n] * e_w[n] * e_r[m]);
      }
    }
  }
}

// ---------- fused gate+up MX-fp8 GEMM: BM=256, 512 thr / 8 waves ----------
// Per-wave tile unchanged (4x2 frags, 16 accs, 16 mx8/step — R10 lesson:
// never grow per-wave resources). Block grows instead: LDS 48KB -> >=2
// blocks/CU = 16 waves/CU (vs ~9) for drain-hiding; W panels reused across
// 256 rows (halves W traffic). Same K-order per output -> identical numerics.
__global__ void __launch_bounds__(512) gemm_gu(
    const unsigned char* __restrict__ X, const unsigned char* __restrict__ Wg,
    const unsigned char* __restrict__ Wu, int M, int N, int K,
    unsigned char* __restrict__ out8, float inv) {
  constexpr int BM = 256, BN = 64, BK = 128;
  constexpr int TM = 4, TN = 2;
  __shared__ __attribute__((aligned(16))) unsigned char aT[BM * BK];  // 32 KB
  __shared__ __attribute__((aligned(16))) unsigned char gT[BN * BK];  // 8 KB
  __shared__ __attribute__((aligned(16))) unsigned char uT[BN * BK];  // 8 KB
  const int tid = threadIdx.x;
  const int lane = tid & 63, wave = tid >> 6;       // 8 waves
  const int wm = wave >> 1, wn = wave & 1;          // 4 M-waves x 2 N-waves
  const int lm = lane & 15, quad = lane >> 4;
  const long bm0 = (long)blockIdx.y * BM;
  const long bn0 = (long)blockIdx.x * BN;
  const int wb = tid & ~63;

  f32x4 accg[TM][TN], accu[TM][TN];
#pragma unroll
  for (int i = 0; i < TM; i++)
#pragma unroll
    for (int j = 0; j < TN; j++) {
      accg[i][j] = (f32x4){0.f, 0.f, 0.f, 0.f};
      accu[i][j] = (f32x4){0.f, 0.f, 0.f, 0.f};
    }

  for (int k0 = 0; k0 < K; k0 += BK) {
#pragma unroll
    for (int it = 0; it < 4; ++it) {       // A: 256 rows x 8 chunks(16B) = 2048 slots
      int slot = it * 512 + tid;
      int r = slot >> 3, cp = slot & 7, c = cp ^ (r & 7);
      async_ld16(X + (bm0 + r) * (long)K + k0 + c * 16, aT + (it * 512 + wb) * 16);
    }
    {                                       // Wg: 64 rows x 8 chunks = 512 slots
      int r = tid >> 3, cp = tid & 7, c = cp ^ (r & 7);
      async_ld16(Wg + (bn0 + r) * (long)K + k0 + c * 16, gT + wb * 16);
      async_ld16(Wu + (bn0 + r) * (long)K + k0 + c * 16, uT + wb * 16);
    }
    __syncthreads();
    int8v a[TM], g[TN], u[TN];
#pragma unroll
    for (int i = 0; i < TM; i++) a[i] = rd8(aT, wm * 64 + i * 16 + lm, quad);
#pragma unroll
    for (int j = 0; j < TN; j++) {
      g[j] = rd8(gT, wn * 32 + j * 16 + lm, quad);
      u[j] = rd8(uT, wn * 32 + j * 16 + lm, quad);
    }
#pragma unroll
    for (int i = 0; i < TM; i++)
#pragma unroll
      for (int j = 0; j < TN; j++) {
        accg[i][j] = mx8(a[i], g[j], accg[i][j]);
        accu[i][j] = mx8(a[i], u[j], accu[i][j]);
      }
    __syncthreads();
  }
#pragma unroll
  for (int i = 0; i < TM; i++) {
#pragma unroll
    for (int j = 0; j < TN; j++) {
#pragma unroll
      for (int r = 0; r < 4; r++) {
        const long m = bm0 + wm * 64 + i * 16 + quad * 4 + r;
        const long n = bn0 + wn * 32 + j * 16 + lm;
        const float gg = accg[i][j][r] * inv;
        const float uu = accu[i][j][r] * inv;
        const float s = gg / (1.f + __expf(-gg));
        out8[m * N + n] = f2f8(s * uu);
      }
    }
  }
}

// ---------- MX-fp8 GEMM (down proj), BN=128 (R9-proven): 16 mx8/K-step ----------
__global__ void __launch_bounds__(256) gemm_f8(
    const unsigned char* __restrict__ X, const unsigned char* __restrict__ W,
    int M, int N, int K,
    float* __restrict__ outf, const float* __restrict__ e_f, float inv) {
  constexpr int BM = 128, BN = 128, BK = 128;
  constexpr int TM = 4, TN = 4;
  __shared__ __attribute__((aligned(16))) unsigned char aT[BM * BK];  // 16 KB
  __shared__ __attribute__((aligned(16))) unsigned char bT[BN * BK];  // 16 KB
  const int tid = threadIdx.x;
  const int lane = tid & 63, wave = tid >> 6;
  const int wm = wave >> 1, wn = wave & 1;
  const int lm = lane & 15, quad = lane >> 4;
  const long bm0 = (long)blockIdx.y * BM;
  const long bn0 = (long)blockIdx.x * BN;
  const int wb = tid & ~63;

  f32x4 acc[TM][TN];
#pragma unroll
  for (int i = 0; i < TM; i++)
#pragma unroll
    for (int j = 0; j < TN; j++) acc[i][j] = (f32x4){0.f, 0.f, 0.f, 0.f};

  for (int k0 = 0; k0 < K; k0 += BK) {
#pragma unroll
    for (int it = 0; it < 4; ++it) {       // A: 128 rows x 8 chunks
      int slot = it * 256 + tid;
      int r = slot >> 3, cp = slot & 7, c = cp ^ (r & 7);
      async_ld16(X + (bm0 + r) * (long)K + k0 + c * 16, aT + (it * 256 + wb) * 16);
    }
#pragma unroll
    for (int it = 0; it < 4; ++it) {       // B: 128 rows x 8 chunks
      int slot = it * 256 + tid;
      int r = slot >> 3, cp = slot & 7, c = cp ^ (r & 7);
      async_ld16(W + (bn0 + r) * (long)K + k0 + c * 16, bT + (it * 256 + wb) * 16);
    }
    __syncthreads();
    int8v a[TM], b[TN];
#pragma unroll
    for (int i = 0; i < TM; i++) a[i] = rd8(aT, wm * 64 + i * 16 + lm, quad);
#pragma unroll
    for (int j = 0; j < TN; j++) b[j] = rd8(bT, wn * 64 + j * 16 + lm, quad);
#pragma unroll
    for (int i = 0; i < TM; i++)
#pragma unroll
      for (int j = 0; j < TN; j++)
        acc[i][j] = mx8(a[i], b[j], acc[i][j]);
    __syncthreads();
  }
#pragma unroll
  for (int i = 0; i < TM; i++) {
#pragma unroll
    for (int j = 0; j < TN; j++) {
#pragma unroll
      for (int r = 0; r < 4; r++) {
        const long m = bm0 + wm * 64 + i * 16 + quad * 4 + r;
        const long n = bn0 + wn * 64 + j * 16 + lm;
        const long idx = m * N + n;
        outf[idx] = acc[i][j][r] * inv + e_f[idx];
      }
    }
  }
}

// ---------- launch ----------
extern "C" void kernel_launch(void* const* d_in, const int* in_sizes, int n_in,
                              void* d_out, int out_size, void* d_ws, size_t ws_size,
                              hipStream_t stream) {
  const float* x     = (const float*)d_in[0];   // (4,2048,1024)
  const float* A     = (const float*)d_in[1];   // (64,64)
  const float* B     = (const float*)d_in[2];   // (64,1024)
  const float* C     = (const float*)d_in[3];   // (1024,64)
  const float* D     = (const float*)d_in[4];   // (1024,)
  const float* logdt = (const float*)d_in[5];   // (1024,)
  const float* wg    = (const float*)d_in[6];   // (4096,1024)
  const float* wu    = (const float*)d_in[7];   // (4096,1024)
  const float* wd    = (const float*)d_in[8];   // (1024,4096)
  const float* ln1   = (const float*)d_in[9];
  const float* ln2   = (const float*)d_in[10];
  float* out = (float*)d_out;

  char* p = (char*)d_ws;
  auto alloc = [&](size_t bytes) { char* q = p; p += (bytes + 255) & ~(size_t)255; return q; };
  float* Abar  = (float*)alloc(64 * 64 * 4);
  float* A64   = (float*)alloc(64 * 64 * 4);
  float* zend  = (float*)alloc(4 * 32 * 64 * 4);
  float* carry = (float*)alloc(4 * 32 * 64 * 4);
  float* rs    = (float*)alloc((size_t)8192 * 4);
  float* U     = (float*)alloc((size_t)8192 * 64 * 4);
  unsigned short* S    = (unsigned short*)alloc((size_t)8192 * 64 * 2);
  unsigned short* Bb   = (unsigned short*)alloc((size_t)64 * 1024 * 2);
  unsigned short* Cb   = (unsigned short*)alloc((size_t)1024 * 64 * 2);
  unsigned char*  wg8  = (unsigned char*)alloc((size_t)4096 * 1024);
  unsigned char*  wu8  = (unsigned char*)alloc((size_t)4096 * 1024);
  unsigned char*  wd8  = (unsigned char*)alloc((size_t)1024 * 4096);
  unsigned short* xnb  = (unsigned short*)alloc((size_t)8192 * 1024 * 2);
  unsigned char*  hn8  = (unsigned char*)alloc((size_t)8192 * 1024);
  float* h             = (float*)alloc((size_t)8192 * 1024 * 4);
  unsigned char*  act8 = (unsigned char*)alloc((size_t)8192 * 4096);

  const size_t NWG = (size_t)4096 * 1024;

  // prep (block 0) + Bb/Cb riders (1..32) + fused rmsnorm1+rs (33..2080)
  prep_combo<<<33 + 2048, 1024, 0, stream>>>(
      A, logdt, Abar, A64, B, C, Bb, Cb, x, ln1, xnb, rs);
  // U = xn @ B_bar^T
  gemm_bt<32, 64, 2, 2, 0><<<dim3(1, 256), 256, 0, stream>>>(
      xnb, Bb, 8192, 64, 1024, U, nullptr, nullptr, nullptr, nullptr);
  // scan pass 1 (zero-init, chunk ends) + wg*64->fp8 convert (vectorized)
  scan_combo<0><<<32 + 1024, 256, 0, stream>>>(
      U, Abar, nullptr, zend, S, wg, wg8, NWG);
  // carry recurrence + wu*64->fp8 convert (vectorized)
  carry_combo<<<1 + 1024, 256, 0, stream>>>(zend, A64, carry, wu, wu8, NWG);
  // scan pass 2 (carry-init, all states bf16) + wd*64->fp8 convert (vectorized)
  scan_combo<1><<<32 + 1024, 256, 0, stream>>>(
      U, Abar, carry, zend, S, wd, wd8, NWG);
  // h = S @ C^T + x*(1 + D*ln1*rs)   (residual + D*xn, fp32 recompute)
  gemm_bt<128, 128, 2, 2, 5><<<dim3(8, 64), 256, 0, stream>>>(
      S, Cb, 8192, 1024, 64, h, x, D, ln1, rs);
  rmsnorm_f8<<<8192, 256, 0, stream>>>(h, ln2, (unsigned int*)hn8);
  // act = silu(hn @ wg^T / 64) * (hn @ wu^T / 64) -> fp8  (BM=256, 512 thr)
  gemm_gu<<<dim3(64, 32), 512, 0, stream>>>(
      hn8, wg8, wu8, 8192, 4096, 1024, act8, 1.f / 64.f);
  // out = h + (act8 @ wd8^T)/64   (BN=128: 16 mx8/K-step)
  gemm_f8<<<dim3(8, 64), 256, 0, stream>>>(
      act8, wd8, 8192, 1024, 4096, out, h, 1.f / 64.f);
}

// Round 13
// 376.119 us; speedup vs baseline: 1.0729x; 1.0729x over previous
//
#include <hip/hip_runtime.h>
#include <hip/hip_bf16.h>
#include <math.h>

// ---------- helpers ----------
typedef __attribute__((ext_vector_type(8))) short short8;   // 8 bf16 = 4 VGPR (MFMA A/B frag)
typedef __attribute__((ext_vector_type(4))) float f32x4;    // MFMA C/D frag
typedef __attribute__((ext_vector_type(4))) int int4v;
typedef __attribute__((ext_vector_type(8))) int int8v;

__device__ __forceinline__ unsigned short f2b(float x) {    // fp32 -> bf16 bits, RNE
  union { float f; unsigned int u; } v; v.f = x;
  unsigned int r = v.u + 0x7fffu + ((v.u >> 16) & 1u);
  return (unsigned short)(r >> 16);
}
__device__ __forceinline__ float b2f(unsigned short u) {
  union { unsigned int u; float f; } v; v.u = ((unsigned int)u) << 16;
  return v.f;
}
// fp32 -> OCP e4m3fn byte (software fallback), RNE
__device__ __forceinline__ unsigned char f2f8_sw(float x) {
  float a = fabsf(x);
  unsigned char s = (x < 0.f) ? 0x80 : 0x00;
  if (a >= 464.f) return s | 0x7E;
  union { float f; unsigned u; } v; v.f = a;
  int e = (int)(v.u >> 23) - 127;
  if (e < -6) {
    int q = (int)rintf(a * 512.f);
    if (q >= 8) return s | 0x08;
    return s | (unsigned char)q;
  }
  unsigned mant = v.u & 0x7FFFFF;
  unsigned keep = mant >> 20;
  unsigned rest = mant & 0xFFFFF;
  if (rest > 0x80000u || (rest == 0x80000u && (keep & 1))) keep++;
  unsigned exp8 = (unsigned)(e + 7);
  if (keep == 8) { keep = 0; exp8++; }
  if (exp8 >= 15 && keep >= 7) return s | 0x7E;
  return s | (unsigned char)((exp8 << 3) | keep);
}
#if __has_builtin(__builtin_amdgcn_cvt_pk_fp8_f32)
__device__ __forceinline__ unsigned char f2f8(float x) {
  return (unsigned char)(__builtin_amdgcn_cvt_pk_fp8_f32(x, x, 0, false) & 0xFF);
}
__device__ __forceinline__ unsigned int f8pack4(float a, float b, float c, float d) {
  int w0 = __builtin_amdgcn_cvt_pk_fp8_f32(a, b, 0, false);
  return (unsigned int)__builtin_amdgcn_cvt_pk_fp8_f32(c, d, w0, true);
}
#else
__device__ __forceinline__ unsigned char f2f8(float x) { return f2f8_sw(x); }
__device__ __forceinline__ unsigned int f8pack4(float a, float b, float c, float d) {
  return (unsigned)f2f8_sw(a) | ((unsigned)f2f8_sw(b) << 8) |
         ((unsigned)f2f8_sw(c) << 16) | ((unsigned)f2f8_sw(d) << 24);
}
#endif
__device__ __forceinline__ void async_ld16(const void* g, void* l) {
  __builtin_amdgcn_global_load_lds(
      (const __attribute__((address_space(1))) void*)g,
      (__attribute__((address_space(3))) void*)l, 16, 0, 0);
}

// vectorized weight->fp8 rider: float4 load + packed uint store (G13).
__device__ __forceinline__ void conv_rider(
    const float* __restrict__ csrc, unsigned char* __restrict__ cdst,
    size_t ccount, size_t tidg, size_t nthr) {
  const float4* src4 = (const float4*)csrc;
  unsigned int* dst4 = (unsigned int*)cdst;
  const size_t ng = ccount >> 2;
  for (size_t id = tidg; id < ng; id += nthr) {
    const float4 v = src4[id];
    dst4[id] = f8pack4(v.x * 64.f, v.y * 64.f, v.z * 64.f, v.w * 64.f);
  }
}

// MX-scaled fp8 K=128 MFMA with unit scales (== exact fp8 GEMM at 2x rate).
__device__ __forceinline__ f32x4 mx8(int8v a, int8v b, f32x4 c) {
#if __has_builtin(__builtin_amdgcn_mfma_scale_f32_16x16x128_f8f6f4)
  return __builtin_amdgcn_mfma_scale_f32_16x16x128_f8f6f4(
      a, b, c, 0, 0, 0, 0x7F7F7F7F, 0, 0x7F7F7F7F);
#else
  union { int8v v; long l[4]; } av, bv; av.v = a; bv.v = b;
#pragma unroll
  for (int j = 0; j < 4; j++)
    c = __builtin_amdgcn_mfma_f32_16x16x32_fp8_fp8(av.l[j], bv.l[j], c, 0, 0, 0);
  return c;
#endif
}

// conflict-free fragment read: two b128 at 16B granules (2q)^(r&7), (2q+1)^(r&7).
__device__ __forceinline__ int8v rd8(const unsigned char* tb, int r, int q) {
  union { int8v v; int4v h[2]; } x;
  x.h[0] = *(const int4v*)(tb + (size_t)((r << 3) + ((2 * q)     ^ (r & 7))) * 16);
  x.h[1] = *(const int4v*)(tb + (size_t)((r << 3) + ((2 * q + 1) ^ (r & 7))) * 16);
  return x.v;
}

// ---------- prep (block 0) + Bb/Cb riders (1..32) + fused RMSNorm1 (33..) ----------
__global__ __launch_bounds__(1024) void prep_combo(
    const float* __restrict__ A, const float* __restrict__ logdt,
    float* __restrict__ Abar, float* __restrict__ A64,
    const float* __restrict__ B, const float* __restrict__ Cm,
    unsigned short* __restrict__ Bb, unsigned short* __restrict__ Cb,
    const float* __restrict__ x, const float* __restrict__ w1,
    unsigned short* __restrict__ xnb, float* __restrict__ rs_out) {
  __shared__ float red[16];
  __shared__ float Ms[4096], T[4096], P[4096];
  __shared__ float wsum2[16];
  const int tid = threadIdx.x;
  if (blockIdx.x >= 33) {                    // fused rmsnorm: 4 rows / block
    const int sub = tid >> 8, t = tid & 255;
    const size_t row = (size_t)(blockIdx.x - 33) * 4 + sub;
    const float4 v = ((const float4*)(x + row * 1024))[t];
    float ss = v.x * v.x + v.y * v.y + v.z * v.z + v.w * v.w;
#pragma unroll
    for (int off = 32; off > 0; off >>= 1) ss += __shfl_down(ss, off);
    if ((t & 63) == 0) wsum2[(sub << 2) | (t >> 6)] = ss;
    __syncthreads();
    const float tot = wsum2[sub << 2] + wsum2[(sub << 2) | 1] +
                      wsum2[(sub << 2) | 2] + wsum2[(sub << 2) | 3];
    const float rs = rsqrtf(tot * (1.f / 1024.f) + 1e-6f);
    if (t == 0) rs_out[row] = rs;
    const float4 wv = ((const float4*)w1)[t];
    ushort4 o;
    o.x = f2b(v.x * rs * wv.x); o.y = f2b(v.y * rs * wv.y);
    o.z = f2b(v.z * rs * wv.z); o.w = f2b(v.w * rs * wv.w);
    ((ushort4*)(xnb + row * 1024))[t] = o;
    return;
  }
  if (blockIdx.x != 0) {                     // Bb/Cb riders (32 blocks)
    const size_t NB = 65536, NC = 65536;
    size_t base = (size_t)(blockIdx.x - 1) * 1024 + tid;
    const size_t stride = 32 * 1024;
    for (size_t id = base; id < NB + NC; id += stride) {
      if (id < NB) { int k = (int)(id & 1023); Bb[id] = f2b(B[id] * expf(logdt[k])); }
      else Cb[id - NB] = f2b(Cm[id - NB]);
    }
    return;
  }
  const int c = tid & 63;
  const int w = tid >> 6;
  float e = expf(logdt[tid]);
#pragma unroll
  for (int off = 32; off > 0; off >>= 1) e += __shfl_down(e, off);
  if (c == 0) red[w] = e;
  __syncthreads();
  if (tid == 0) {
    float s = 0.f;
    for (int i = 0; i < 16; i++) s += red[i];
    red[0] = s * (1.f / 1024.f);
  }
  __syncthreads();
  const float mdt = red[0];
  {
    float m0 = A[tid] * mdt, m1 = A[tid + 1024] * mdt,
          m2 = A[tid + 2048] * mdt, m3 = A[tid + 3072] * mdt;
    Ms[tid] = m0; Ms[tid + 1024] = m1; Ms[tid + 2048] = m2; Ms[tid + 3072] = m3;
    T[tid] = m0; T[tid + 1024] = m1; T[tid + 2048] = m2; T[tid + 3072] = m3;
    P[tid] = m0 + ((tid >> 6) == (tid & 63) ? 1.f : 0.f);
    P[tid + 1024] = m1 + (((tid + 1024) >> 6) == ((tid + 1024) & 63) ? 1.f : 0.f);
    P[tid + 2048] = m2 + (((tid + 2048) >> 6) == ((tid + 2048) & 63) ? 1.f : 0.f);
    P[tid + 3072] = m3 + (((tid + 3072) >> 6) == ((tid + 3072) & 63) ? 1.f : 0.f);
  }
  __syncthreads();
  float colM[64];
#pragma unroll
  for (int j = 0; j < 64; j++) colM[j] = Ms[j * 64 + c];
  for (int k = 2; k <= 6; k++) {
    const float inv = 1.f / (float)k;
    float accs[4];
#pragma unroll
    for (int i = 0; i < 4; i++) {
      const int r = w + 16 * i;
      const float4* Trow = (const float4*)(T + r * 64);
      float a0 = 0.f, a1 = 0.f, a2 = 0.f, a3 = 0.f;
#pragma unroll
      for (int j4 = 0; j4 < 16; j4++) {
        const float4 t = Trow[j4];
        a0 += t.x * colM[4 * j4 + 0]; a1 += t.y * colM[4 * j4 + 1];
        a2 += t.z * colM[4 * j4 + 2]; a3 += t.w * colM[4 * j4 + 3];
      }
      accs[i] = ((a0 + a1) + (a2 + a3)) * inv;
    }
    __syncthreads();
#pragma unroll
    for (int i = 0; i < 4; i++) {
      const int r = w + 16 * i;
      T[r * 64 + c] = accs[i];
      P[r * 64 + c] += accs[i];
    }
    __syncthreads();
  }
#pragma unroll
  for (int i = 0; i < 4; i++) {
    const int r = w + 16 * i;
    Abar[r * 64 + c] = P[r * 64 + c];
    T[r * 64 + c] = P[r * 64 + c];
  }
  __syncthreads();
  for (int sq = 0; sq < 6; sq++) {
    float colT[64];
#pragma unroll
    for (int j = 0; j < 64; j++) colT[j] = T[j * 64 + c];
    float accs[4];
#pragma unroll
    for (int i = 0; i < 4; i++) {
      const int r = w + 16 * i;
      const float4* Trow = (const float4*)(T + r * 64);
      float a0 = 0.f, a1 = 0.f, a2 = 0.f, a3 = 0.f;
#pragma unroll
      for (int j4 = 0; j4 < 16; j4++) {
        const float4 t = Trow[j4];
        a0 += t.x * colT[4 * j4 + 0]; a1 += t.y * colT[4 * j4 + 1];
        a2 += t.z * colT[4 * j4 + 2]; a3 += t.w * colT[4 * j4 + 3];
      }
      accs[i] = (a0 + a1) + (a2 + a3);
    }
    __syncthreads();
#pragma unroll
    for (int i = 0; i < 4; i++) T[(w + 16 * i) * 64 + c] = accs[i];
    __syncthreads();
  }
#pragma unroll
  for (int i = 0; i < 4; i++) {
    const int r = w + 16 * i;
    A64[r * 64 + c] = T[r * 64 + c];
  }
}

// ---------- RMSNorm (row = 1024) -> fp8 e4m3 ----------
__global__ __launch_bounds__(256) void rmsnorm_f8(
    const float* __restrict__ x, const float* __restrict__ w,
    unsigned int* __restrict__ out) {       // 4 fp8 per uint
  const size_t row = blockIdx.x;
  const int tid = threadIdx.x;
  const float4 v = ((const float4*)(x + row * 1024))[tid];
  float ss = v.x * v.x + v.y * v.y + v.z * v.z + v.w * v.w;
#pragma unroll
  for (int off = 32; off > 0; off >>= 1) ss += __shfl_down(ss, off);
  __shared__ float wsum[4];
  if ((tid & 63) == 0) wsum[tid >> 6] = ss;
  __syncthreads();
  const float tot = wsum[0] + wsum[1] + wsum[2] + wsum[3];
  const float rs = rsqrtf(tot * (1.f / 1024.f) + 1e-6f);
  const float4 wv = ((const float4*)w)[tid];
  out[row * 256 + tid] =
      f8pack4(v.x * rs * wv.x, v.y * rs * wv.y, v.z * rs * wv.z, v.w * rs * wv.w);
}

// ---------- scan (32 blocks, 4 chunk-waves each) + fp8 weight-convert riders ----------
// Barrier-free (wave-private s-slice) + next-step prefetch; R6-verified.
template <int STORE_S>
__global__ __launch_bounds__(256) void scan_combo(
    const float* __restrict__ U, const float* __restrict__ Abar,
    const float* __restrict__ carry, float* __restrict__ zend,
    unsigned short* __restrict__ S,
    const float* __restrict__ csrc, unsigned char* __restrict__ cdst, size_t ccount) {
  constexpr int SCAN_BLOCKS = 32;
  __shared__ float s[4][64];
  if (blockIdx.x >= SCAN_BLOCKS) {
    conv_rider(csrc, cdst, ccount,
               (size_t)(blockIdx.x - SCAN_BLOCKS) * 256 + threadIdx.x,
               (size_t)(gridDim.x - SCAN_BLOCKS) * 256);
    return;
  }
  const int wave = threadIdx.x >> 6, i = threadIdx.x & 63;
  const int task = blockIdx.x * 4 + wave;
  const int b = task >> 5, c = task & 31;
  float a[64];
#pragma unroll
  for (int j = 0; j < 64; j++) a[j] = Abar[i * 64 + j];
  float cur = STORE_S ? carry[(b * 32 + c) * 64 + i] : 0.f;
  const float* Ub = U + ((size_t)(b * 2048 + c * 64)) * 64;
  float u = Ub[i];                          // prefetched element for t=0
  for (int t = 0; t < 64; t++) {
    s[wave][i] = cur;
    float u_next = 0.f;
    if (t + 1 < 64) u_next = Ub[(t + 1) * 64 + i];   // prefetch next step
    const float4* s4 = (const float4*)s[wave];
    float a0 = u, a1 = 0.f, a2 = 0.f, a3 = 0.f;
#pragma unroll
    for (int j = 0; j < 16; j++) {
      float4 v = s4[j];
      a0 += a[4 * j + 0] * v.x; a1 += a[4 * j + 1] * v.y;
      a2 += a[4 * j + 2] * v.z; a3 += a[4 * j + 3] * v.w;
    }
    cur = (a0 + a1) + (a2 + a3);
    if (STORE_S) S[((size_t)(b * 2048 + c * 64 + t)) * 64 + i] = f2b(cur);
    u = u_next;
  }
  if (!STORE_S) zend[(b * 32 + c) * 64 + i] = cur;
}

// ---------- carry recurrence (block 0) + fp8 weight-convert riders ----------
__global__ __launch_bounds__(256) void carry_combo(
    const float* __restrict__ zend, const float* __restrict__ A64,
    float* __restrict__ carry,
    const float* __restrict__ csrc, unsigned char* __restrict__ cdst, size_t ccount) {
  __shared__ float s[4][64];
  if (blockIdx.x != 0) {
    conv_rider(csrc, cdst, ccount,
               (size_t)(blockIdx.x - 1) * 256 + threadIdx.x,
               (size_t)(gridDim.x - 1) * 256);
    return;
  }
  const int b = threadIdx.x >> 6, i = threadIdx.x & 63;
  float a[64];
#pragma unroll
  for (int j = 0; j < 64; j++) a[j] = A64[i * 64 + j];
  float cur = 0.f;
  float z = zend[(b * 32 + 0) * 64 + i];
  for (int c = 0; c < 32; c++) {
    carry[(b * 32 + c) * 64 + i] = cur;
    s[b][i] = cur;
    float z_next = 0.f;
    if (c + 1 < 32) z_next = zend[(b * 32 + c + 1) * 64 + i];
    const float4* s4 = (const float4*)s[b];
    float a0 = z, a1 = 0.f, a2 = 0.f, a3 = 0.f;
#pragma unroll
    for (int j = 0; j < 16; j++) {
      float4 v = s4[j];
      a0 += a[4 * j + 0] * v.x; a1 += a[4 * j + 1] * v.y;
      a2 += a[4 * j + 2] * v.z; a3 += a[4 * j + 3] * v.w;
    }
    cur = (a0 + a1) + (a2 + a3);
    z = z_next;
  }
}

// ---------- bf16 MFMA GEMM:  C(M,N) = X(M,K) @ W(N,K)^T ----------
// EPI: 0 = fp32 store
//      5 = acc + e_f*(1 + e_d[n]*e_w[n]*e_r[m]) -> fp32
template <int BM, int BN, int WAVES_M, int WAVES_N, int EPI>
__global__ void __launch_bounds__(256) gemm_bt(
    const unsigned short* __restrict__ X, const unsigned short* __restrict__ W,
    int M, int N, int K,
    float* __restrict__ outf, const float* __restrict__ e_f,
    const float* __restrict__ e_d, const float* __restrict__ e_w,
    const float* __restrict__ e_r) {
  constexpr int BK = 64;
  constexpr int SM = BM / WAVES_M, SN = BN / WAVES_N;
  constexpr int TM = SM / 16, TN = SN / 16;
  __shared__ unsigned short aT[BM * BK];
  __shared__ unsigned short bT[BN * BK];
  const int tid = threadIdx.x;
  const int lane = tid & 63, wave = tid >> 6;
  const int wm = wave / WAVES_N, wn = wave % WAVES_N;
  const int lm = lane & 15, quad = lane >> 4;
  const long bm0 = (long)blockIdx.y * BM;
  const long bn0 = (long)blockIdx.x * BN;
  const int wb = tid & ~63;

  f32x4 acc[TM][TN];
#pragma unroll
  for (int i = 0; i < TM; i++)
#pragma unroll
    for (int j = 0; j < TN; j++) acc[i][j] = (f32x4){0.f, 0.f, 0.f, 0.f};

  for (int k0 = 0; k0 < K; k0 += BK) {
#pragma unroll
    for (int it = 0; it < (BM * 8) / 256; ++it) {
      int slot = it * 256 + tid;
      int r = slot >> 3, cp = slot & 7, c = cp ^ (r & 7);
      async_ld16(X + (bm0 + r) * (long)K + k0 + c * 8, aT + (it * 256 + wb) * 8);
    }
#pragma unroll
    for (int it = 0; it < (BN * 8) / 256; ++it) {
      int slot = it * 256 + tid;
      int r = slot >> 3, cp = slot & 7, c = cp ^ (r & 7);
      async_ld16(W + (bn0 + r) * (long)K + k0 + c * 8, bT + (it * 256 + wb) * 8);
    }
    __syncthreads();
#pragma unroll
    for (int kk = 0; kk < BK; kk += 32) {
      const int cch = (kk >> 3) + quad;
      short8 af[TM], bf[TN];
#pragma unroll
      for (int i = 0; i < TM; i++) {
        int r = wm * SM + i * 16 + lm;
        af[i] = *(const short8*)(aT + (r * 8 + (cch ^ (r & 7))) * 8);
      }
#pragma unroll
      for (int j = 0; j < TN; j++) {
        int r = wn * SN + j * 16 + lm;
        bf[j] = *(const short8*)(bT + (r * 8 + (cch ^ (r & 7))) * 8);
      }
#pragma unroll
      for (int i = 0; i < TM; i++)
#pragma unroll
        for (int j = 0; j < TN; j++)
          acc[i][j] = __builtin_amdgcn_mfma_f32_16x16x32_bf16(af[i], bf[j], acc[i][j], 0, 0, 0);
    }
    __syncthreads();
  }
#pragma unroll
  for (int i = 0; i < TM; i++) {
#pragma unroll
    for (int j = 0; j < TN; j++) {
#pragma unroll
      for (int r = 0; r < 4; r++) {
        const long m = bm0 + wm * SM + i * 16 + quad * 4 + r;
        const long n = bn0 + wn * SN + j * 16 + lm;
        const long idx = m * N + n;
        const float v = acc[i][j][r];
        if (EPI == 0) outf[idx] = v;
        else if (EPI == 5)
          outf[idx] = v + e_f[idx] * (1.f + e_d[n] * e_w[n] * e_r[m]);
      }
    }
  }
}

// ---------- fused gate+up MX-fp8 GEMM (R11-proven: BM=128, BN=64, 256 thr) ----------
// Final config. Three-way confirmed rule (R1/R10/R12): per-wave tile 4x2,
// 256 threads, >=2 independent blocks/CU. Waves within a block cannot hide
// each other's drain (same barrier); only independent blocks can.
__global__ void __launch_bounds__(256) gemm_gu(
    const unsigned char* __restrict__ X, const unsigned char* __restrict__ Wg,
    const unsigned char* __restrict__ Wu, int M, int N, int K,
    unsigned char* __restrict__ out8, float inv) {
  constexpr int BM = 128, BN = 64, BK = 128;
  constexpr int TM = 4, TN = 2;
  __shared__ __attribute__((aligned(16))) unsigned char aT[BM * BK];  // 16 KB
  __shared__ __attribute__((aligned(16))) unsigned char gT[BN * BK];  // 8 KB
  __shared__ __attribute__((aligned(16))) unsigned char uT[BN * BK];  // 8 KB
  const int tid = threadIdx.x;
  const int lane = tid & 63, wave = tid >> 6;
  const int wm = wave >> 1, wn = wave & 1;
  const int lm = lane & 15, quad = lane >> 4;
  const long bm0 = (long)blockIdx.y * BM;
  const long bn0 = (long)blockIdx.x * BN;
  const int wb = tid & ~63;

  f32x4 accg[TM][TN], accu[TM][TN];
#pragma unroll
  for (int i = 0; i < TM; i++)
#pragma unroll
    for (int j = 0; j < TN; j++) {
      accg[i][j] = (f32x4){0.f, 0.f, 0.f, 0.f};
      accu[i][j] = (f32x4){0.f, 0.f, 0.f, 0.f};
    }

  for (int k0 = 0; k0 < K; k0 += BK) {
#pragma unroll
    for (int it = 0; it < 4; ++it) {       // A: 128 rows x 8 chunks(16B)
      int slot = it * 256 + tid;
      int r = slot >> 3, cp = slot & 7, c = cp ^ (r & 7);
      async_ld16(X + (bm0 + r) * (long)K + k0 + c * 16, aT + (it * 256 + wb) * 16);
    }
#pragma unroll
    for (int it = 0; it < 2; ++it) {       // Wg: 64 rows x 8 chunks
      int slot = it * 256 + tid;
      int r = slot >> 3, cp = slot & 7, c = cp ^ (r & 7);
      async_ld16(Wg + (bn0 + r) * (long)K + k0 + c * 16, gT + (it * 256 + wb) * 16);
    }
#pragma unroll
    for (int it = 0; it < 2; ++it) {       // Wu
      int slot = it * 256 + tid;
      int r = slot >> 3, cp = slot & 7, c = cp ^ (r & 7);
      async_ld16(Wu + (bn0 + r) * (long)K + k0 + c * 16, uT + (it * 256 + wb) * 16);
    }
    __syncthreads();
    int8v a[TM], g[TN], u[TN];
#pragma unroll
    for (int i = 0; i < TM; i++) a[i] = rd8(aT, wm * 64 + i * 16 + lm, quad);
#pragma unroll
    for (int j = 0; j < TN; j++) {
      g[j] = rd8(gT, wn * 32 + j * 16 + lm, quad);
      u[j] = rd8(uT, wn * 32 + j * 16 + lm, quad);
    }
#pragma unroll
    for (int i = 0; i < TM; i++)
#pragma unroll
      for (int j = 0; j < TN; j++) {
        accg[i][j] = mx8(a[i], g[j], accg[i][j]);
        accu[i][j] = mx8(a[i], u[j], accu[i][j]);
      }
    __syncthreads();
  }
#pragma unroll
  for (int i = 0; i < TM; i++) {
#pragma unroll
    for (int j = 0; j < TN; j++) {
#pragma unroll
      for (int r = 0; r < 4; r++) {
        const long m = bm0 + wm * 64 + i * 16 + quad * 4 + r;
        const long n = bn0 + wn * 32 + j * 16 + lm;
        const float gg = accg[i][j][r] * inv;
        const float uu = accu[i][j][r] * inv;
        const float s = gg / (1.f + __expf(-gg));
        out8[m * N + n] = f2f8(s * uu);
      }
    }
  }
}

// ---------- MX-fp8 GEMM (down proj), BN=128 (R9-proven): 16 mx8/K-step ----------
__global__ void __launch_bounds__(256) gemm_f8(
    const unsigned char* __restrict__ X, const unsigned char* __restrict__ W,
    int M, int N, int K,
    float* __restrict__ outf, const float* __restrict__ e_f, float inv) {
  constexpr int BM = 128, BN = 128, BK = 128;
  constexpr int TM = 4, TN = 4;
  __shared__ __attribute__((aligned(16))) unsigned char aT[BM * BK];  // 16 KB
  __shared__ __attribute__((aligned(16))) unsigned char bT[BN * BK];  // 16 KB
  const int tid = threadIdx.x;
  const int lane = tid & 63, wave = tid >> 6;
  const int wm = wave >> 1, wn = wave & 1;
  const int lm = lane & 15, quad = lane >> 4;
  const long bm0 = (long)blockIdx.y * BM;
  const long bn0 = (long)blockIdx.x * BN;
  const int wb = tid & ~63;

  f32x4 acc[TM][TN];
#pragma unroll
  for (int i = 0; i < TM; i++)
#pragma unroll
    for (int j = 0; j < TN; j++) acc[i][j] = (f32x4){0.f, 0.f, 0.f, 0.f};

  for (int k0 = 0; k0 < K; k0 += BK) {
#pragma unroll
    for (int it = 0; it < 4; ++it) {       // A: 128 rows x 8 chunks
      int slot = it * 256 + tid;
      int r = slot >> 3, cp = slot & 7, c = cp ^ (r & 7);
      async_ld16(X + (bm0 + r) * (long)K + k0 + c * 16, aT + (it * 256 + wb) * 16);
    }
#pragma unroll
    for (int it = 0; it < 4; ++it) {       // B: 128 rows x 8 chunks
      int slot = it * 256 + tid;
      int r = slot >> 3, cp = slot & 7, c = cp ^ (r & 7);
      async_ld16(W + (bn0 + r) * (long)K + k0 + c * 16, bT + (it * 256 + wb) * 16);
    }
    __syncthreads();
    int8v a[TM], b[TN];
#pragma unroll
    for (int i = 0; i < TM; i++) a[i] = rd8(aT, wm * 64 + i * 16 + lm, quad);
#pragma unroll
    for (int j = 0; j < TN; j++) b[j] = rd8(bT, wn * 64 + j * 16 + lm, quad);
#pragma unroll
    for (int i = 0; i < TM; i++)
#pragma unroll
      for (int j = 0; j < TN; j++)
        acc[i][j] = mx8(a[i], b[j], acc[i][j]);
    __syncthreads();
  }
#pragma unroll
  for (int i = 0; i < TM; i++) {
#pragma unroll
    for (int j = 0; j < TN; j++) {
#pragma unroll
      for (int r = 0; r < 4; r++) {
        const long m = bm0 + wm * 64 + i * 16 + quad * 4 + r;
        const long n = bn0 + wn * 64 + j * 16 + lm;
        const long idx = m * N + n;
        outf[idx] = acc[i][j][r] * inv + e_f[idx];
      }
    }
  }
}

// ---------- launch ----------
extern "C" void kernel_launch(void* const* d_in, const int* in_sizes, int n_in,
                              void* d_out, int out_size, void* d_ws, size_t ws_size,
                              hipStream_t stream) {
  const float* x     = (const float*)d_in[0];   // (4,2048,1024)
  const float* A     = (const float*)d_in[1];   // (64,64)
  const float* B     = (const float*)d_in[2];   // (64,1024)
  const float* C     = (const float*)d_in[3];   // (1024,64)
  const float* D     = (const float*)d_in[4];   // (1024,)
  const float* logdt = (const float*)d_in[5];   // (1024,)
  const float* wg    = (const float*)d_in[6];   // (4096,1024)
  const float* wu    = (const float*)d_in[7];   // (4096,1024)
  const float* wd    = (const float*)d_in[8];   // (1024,4096)
  const float* ln1   = (const float*)d_in[9];
  const float* ln2   = (const float*)d_in[10];
  float* out = (float*)d_out;

  char* p = (char*)d_ws;
  auto alloc = [&](size_t bytes) { char* q = p; p += (bytes + 255) & ~(size_t)255; return q; };
  float* Abar  = (float*)alloc(64 * 64 * 4);
  float* A64   = (float*)alloc(64 * 64 * 4);
  float* zend  = (float*)alloc(4 * 32 * 64 * 4);
  float* carry = (float*)alloc(4 * 32 * 64 * 4);
  float* rs    = (float*)alloc((size_t)8192 * 4);
  float* U     = (float*)alloc((size_t)8192 * 64 * 4);
  unsigned short* S    = (unsigned short*)alloc((size_t)8192 * 64 * 2);
  unsigned short* Bb   = (unsigned short*)alloc((size_t)64 * 1024 * 2);
  unsigned short* Cb   = (unsigned short*)alloc((size_t)1024 * 64 * 2);
  unsigned char*  wg8  = (unsigned char*)alloc((size_t)4096 * 1024);
  unsigned char*  wu8  = (unsigned char*)alloc((size_t)4096 * 1024);
  unsigned char*  wd8  = (unsigned char*)alloc((size_t)1024 * 4096);
  unsigned short* xnb  = (unsigned short*)alloc((size_t)8192 * 1024 * 2);
  unsigned char*  hn8  = (unsigned char*)alloc((size_t)8192 * 1024);
  float* h             = (float*)alloc((size_t)8192 * 1024 * 4);
  unsigned char*  act8 = (unsigned char*)alloc((size_t)8192 * 4096);

  const size_t NWG = (size_t)4096 * 1024;

  // prep (block 0) + Bb/Cb riders (1..32) + fused rmsnorm1+rs (33..2080)
  prep_combo<<<33 + 2048, 1024, 0, stream>>>(
      A, logdt, Abar, A64, B, C, Bb, Cb, x, ln1, xnb, rs);
  // U = xn @ B_bar^T
  gemm_bt<32, 64, 2, 2, 0><<<dim3(1, 256), 256, 0, stream>>>(
      xnb, Bb, 8192, 64, 1024, U, nullptr, nullptr, nullptr, nullptr);
  // scan pass 1 (zero-init, chunk ends) + wg*64->fp8 convert (vectorized)
  scan_combo<0><<<32 + 1024, 256, 0, stream>>>(
      U, Abar, nullptr, zend, S, wg, wg8, NWG);
  // carry recurrence + wu*64->fp8 convert (vectorized)
  carry_combo<<<1 + 1024, 256, 0, stream>>>(zend, A64, carry, wu, wu8, NWG);
  // scan pass 2 (carry-init, all states bf16) + wd*64->fp8 convert (vectorized)
  scan_combo<1><<<32 + 1024, 256, 0, stream>>>(
      U, Abar, carry, zend, S, wd, wd8, NWG);
  // h = S @ C^T + x*(1 + D*ln1*rs)   (residual + D*xn, fp32 recompute)
  gemm_bt<128, 128, 2, 2, 5><<<dim3(8, 64), 256, 0, stream>>>(
      S, Cb, 8192, 1024, 64, h, x, D, ln1, rs);
  rmsnorm_f8<<<8192, 256, 0, stream>>>(h, ln2, (unsigned int*)hn8);
  // act = silu(hn @ wg^T / 64) * (hn @ wu^T / 64) -> fp8  (BN=64: proven)
  gemm_gu<<<dim3(64, 64), 256, 0, stream>>>(
      hn8, wg8, wu8, 8192, 4096, 1024, act8, 1.f / 64.f);
  // out = h + (act8 @ wd8^T)/64   (BN=128: 16 mx8/K-step)
  gemm_f8<<<dim3(8, 64), 256, 0, stream>>>(
      act8, wd8, 8192, 1024, 4096, out, h, 1.f / 64.f);
}